// Round 7
// baseline (128120.935 us; speedup 1.0000x reference)
//
// v7: v6 + software-pipelined agent-scope h loads (PF=32, hA/hB double
// buffer) — attacks the L3-latency MLP bottleneck (VALUBusy 7.7%, ~700cy
// per load, only 4 in flight). FMA order unchanged (ascending c, A then B,
// one chain per (row,quarter)) — bit-exact contract preserved (v4/v5/v6
// all reproduce reference absmax exactly). Round-0 fallback kept.
#include <hip/hip_runtime.h>
#include <hip/hip_cooperative_groups.h>

namespace cg = cooperative_groups;

#define UNITS 3225
#define NBATCH 64
#define NSTEP 500
#define NH_SCALE 0.004472135954999579f   // 0.01*sqrt(2*0.1)
#define NI_SCALE 0.004472135954999579f
#define HSZ 103200000ll                  // 64*500*3225
#define WCT_FLOATS 2731520               // transposed weights
#define WC0_FLOATS 2699776               // round-0 weights (fallback)
#define NBLK7 125
#define NTHR7 512

// ---- original geometry ----
__constant__ int   c_dst[7]  = {0,512,665,1177,1689,2201,2713};
__constant__ int   c_rows[7] = {512,153,512,512,512,512,512};
__constant__ int   c_wid[7]  = {1536,1024,256,512,768,871,1024};
__constant__ int   c_r0s[7]  = {0,512,256,665,0,1689,2201};
__constant__ int   c_r0l[7]  = {665,153,256,512,256,512,1024};
__constant__ int   c_r1s[7]  = {2201,2201,0,0,1177,2713,0};
__constant__ float c_ton[7]  = {0.1f,0.1f,0.6f,0.3f,0.6f,0.1f,0.1f};

// ---- v7 partition (= v5/v6, verified): str,fsi,gpe,stn,snr,thal,alm ----
__constant__ int   c7_rpb[7]  = {16,24,32,32,32,32,24};
__constant__ int   c7_cs[8]   = {0,32,39,55,71,87,103,125};
__constant__ int   c7_wb[8]   = {0,786432,958464,1089536,1351680,1744896,2190848,2731520};

// ---- round-0 fallback tables ----
__constant__ int   c0_cs[8]   = {0,64,84,148,212,276,340,404};
__constant__ int   c0_base[7] = {0,786432,943104,1074176,1336320,1729536,2175488};
__constant__ int   c0_cbase[8]= {0,786432,943104,1074176,1336320,1729536,2175488,2699776};

__device__ __forceinline__ float ht_clip(float w) {
    return fminf(fmaxf(w, 1e-10f), 1.0f);
}

__device__ __forceinline__ float agload(const float* pp) {
    return __hip_atomic_load(pp, __ATOMIC_RELAXED, __HIP_MEMORY_SCOPE_AGENT);
}
__device__ __forceinline__ void agstore(float* pp, float v) {
    __hip_atomic_store(pp, v, __ATOMIC_RELAXED, __HIP_MEMORY_SCOPE_AGENT);
}

// shared weight-value computation: region r, row-in-region i, compact col c
__device__ __forceinline__ float w_val(
    int r, int i, int c,
    const float* __restrict__ str2str, const float* __restrict__ thal2alm,
    const float* __restrict__ thal2str, const float* __restrict__ alm2alm,
    const float* __restrict__ alm2str, const float* __restrict__ alm2thal,
    const float* __restrict__ str2snr, const float* __restrict__ str2gpe,
    const float* __restrict__ gpe2stn, const float* __restrict__ stn2snr,
    const float* __restrict__ snr2thal, const float* __restrict__ fsi2str,
    const float* __restrict__ thal2fsi, const float* __restrict__ alm2fsi,
    const float* __restrict__ fsi2fsi, const int* __restrict__ smask)
{
    int r0l = c_r0l[r];
    int v = (c < r0l) ? (c_r0s[r] + c) : (c_r1s[r] + (c - r0l));
    int rv, j;
    if (v < 512)       { rv = 0; j = v; }
    else if (v < 665)  { rv = 1; j = v - 512; }
    else if (v < 1177) { rv = 2; j = v - 665; }
    else if (v < 1689) { rv = 3; j = v - 1177; }
    else if (v < 2201) { rv = 4; j = v - 1689; }
    else if (v < 2713) { rv = 5; j = v - 2201; }
    else               { rv = 6; j = v - 2713; }
    float val = 0.0f;
    switch (r) {
    case 0:
        if (rv == 0)      val = smask[i*512+j] ? -ht_clip(str2str[i*512+j]) : 0.0f;
        else if (rv == 1) val = -ht_clip(fsi2str[i*153+j]);
        else if (rv == 5) val = (i < 256) ? ht_clip(thal2str[i*512+j]) : 0.0f;
        else              val = (j < 359) ? ht_clip(alm2str[i*512+j]) : 0.0f;
        break;
    case 1:
        if (rv == 1)      val = -ht_clip(fsi2fsi[i*153+j]);
        else if (rv == 5) val = ht_clip(thal2fsi[i*512+j]);
        else              val = (j < 359) ? ht_clip(alm2fsi[i*512+j]) : 0.0f;
        break;
    case 2:
        val = (j >= 256) ? -ht_clip(str2gpe[i*512+j]) : 0.0f;
        break;
    case 3:
        val = -ht_clip(gpe2stn[i*512+j]);
        break;
    case 4:
        if (rv == 0) val = (j < 256) ? -ht_clip(str2snr[i*512+j]) : 0.0f;
        else         val = ht_clip(stn2snr[i*512+j]);
        break;
    case 5:
        if (rv == 4) val = -ht_clip(snr2thal[i*512+j]);
        else         val = (j < 359) ? ht_clip(alm2thal[i*512+j]) : 0.0f;
        break;
    default:
        if (rv == 5) val = ht_clip(thal2alm[i*512+j]);
        else         val = (j < 359) ? ht_clip(alm2alm[i*512+j]) : -ht_clip(alm2alm[i*512+j]);
        break;
    }
    return val;
}

#define WARGS                                                                  \
    const float* __restrict__ str2str, const float* __restrict__ thal2alm,     \
    const float* __restrict__ thal2str, const float* __restrict__ alm2alm,     \
    const float* __restrict__ alm2str, const float* __restrict__ alm2thal,     \
    const float* __restrict__ str2snr, const float* __restrict__ str2gpe,      \
    const float* __restrict__ gpe2stn, const float* __restrict__ stn2snr,      \
    const float* __restrict__ snr2thal, const float* __restrict__ fsi2str,     \
    const float* __restrict__ thal2fsi, const float* __restrict__ alm2fsi,     \
    const float* __restrict__ fsi2fsi, const int* __restrict__ smask
#define WPASS str2str, thal2alm, thal2str, alm2alm, alm2str, alm2thal,         \
    str2snr, str2gpe, gpe2stn, stn2snr, snr2thal, fsi2str, thal2fsi, alm2fsi,  \
    fsi2fsi, smask

// weights transposed per block: Wct[blockbase + c*rpb + q]; also zero barrier cnt
__global__ void build_w_v7(WARGS, float* __restrict__ Wct, unsigned* __restrict__ cnt)
{
    int tid = blockIdx.x * blockDim.x + threadIdx.x;
    if (tid == 0) { cnt[0] = 0u; }
    if (tid >= WCT_FLOATS) return;
    int r = 0;
    while (tid >= c7_wb[r+1]) ++r;
    int local = tid - c7_wb[r];
    int rpb   = c7_rpb[r];
    int width = c_wid[r];
    int bsz   = width * rpb;
    int blk   = local / bsz;
    int rem   = local - blk*bsz;
    int c     = rem / rpb;
    int q     = rem - c*rpb;
    int i     = blk*rpb + q;
    float val = 0.0f;
    if (i < c_rows[r]) val = w_val(r, i, c, WPASS);
    Wct[tid] = val;
}

// round-0 layout (fallback): Wc[blockrowbase + q*width + c]
__global__ void build_w_r0(WARGS, float* __restrict__ Wc)
{
    int tid = blockIdx.x * blockDim.x + threadIdx.x;
    if (tid >= WC0_FLOATS) return;
    int r = 0;
    while (tid >= c0_cbase[r+1]) ++r;
    int local = tid - c0_cbase[r];
    int width = c_wid[r];
    int row = local / width;
    int c = local - row * width;
    Wc[tid] = w_val(r, row, c, WPASS);
}

struct Params {
    const float* __restrict__ inp;
    const float* __restrict__ cue;
    const float* __restrict__ inhib;
    const float* __restrict__ hn;
    const float* __restrict__ xn;
    const float* __restrict__ noise_hid;
    const float* __restrict__ noise_inp;
    const float* __restrict__ inp_w;
    const float* __restrict__ out_w;
    const float* __restrict__ Wc;
    float* __restrict__ hT0;
    float* __restrict__ hT1;
    unsigned* __restrict__ cnt;
    float* __restrict__ out;
};

// grid barrier without cache maintenance (h traffic is agent-scope).
__device__ __forceinline__ void gbarrier(unsigned* cnt, unsigned target)
{
    asm volatile("s_waitcnt vmcnt(0)" ::: "memory");
    __syncthreads();
    if (threadIdx.x == 0) {
        __hip_atomic_fetch_add(cnt, 1u, __ATOMIC_RELAXED, __HIP_MEMORY_SCOPE_AGENT);
        while (__hip_atomic_load(cnt, __ATOMIC_RELAXED, __HIP_MEMORY_SCOPE_AGENT) < target)
            __builtin_amdgcn_s_sleep(2);
    }
    __syncthreads();
    asm volatile("" ::: "memory");
}

// BIT-EXACTNESS CONTRACT (verified: v4/v5/v6 reproduce reference absmax
// exactly): per (row,quarter) one acc chain, segment A then B, strictly
// ascending c; quarters summed ascending; drive order
// mm+tonic -> inp -> cue -> inhib -> noise. Pipelining below only changes
// WHEN loads are issued, never FMA order.
#define PF 32

template<int RPB, int HALF>
__device__ __forceinline__ void fma_batch(
    const float* __restrict__ wq, int cbase, const float* __restrict__ hv,
    float* __restrict__ acc)
{
    #pragma unroll
    for (int j = 0; j < PF; ++j) {
        #pragma unroll
        for (int g = 0; g < HALF/4; ++g) {
            const float4 w4 = *reinterpret_cast<const float4*>(&wq[(cbase + j)*RPB + 4*g]);
            acc[4*g+0] += w4.x * hv[j];
            acc[4*g+1] += w4.y * hv[j];
            acc[4*g+2] += w4.z * hv[j];
            acc[4*g+3] += w4.w * hv[j];
        }
    }
}

template<int RPB, int HALF>
__device__ __forceinline__ void mm_seg_pipe(
    const float* __restrict__ rbl,   // rb + lane
    const float* __restrict__ wq,
    int cfrom, int cto, int abase,   // h addr = (abase + c)*64 + lane
    float* __restrict__ acc)
{
    const int n = cto - cfrom;
    if (n <= 0) return;
    const int nfull = n / PF;
    float hA[PF], hB[PF];
    int c = cfrom;

    if (nfull > 0) {                      // prologue: batch 0 -> hA
        #pragma unroll
        for (int j = 0; j < PF; ++j) hA[j] = agload(&rbl[(abase + c + j)*64]);
    }
    int k = 0;
    for (; k + 2 <= nfull; k += 2) {
        #pragma unroll                    // issue batch k+1 -> hB
        for (int j = 0; j < PF; ++j) hB[j] = agload(&rbl[(abase + c + PF + j)*64]);
        fma_batch<RPB,HALF>(wq, c, hA, acc);          // consume batch k
        c += PF;
        if (k + 2 < nfull) {
            #pragma unroll                // issue batch k+2 -> hA
            for (int j = 0; j < PF; ++j) hA[j] = agload(&rbl[(abase + c + PF + j)*64]);
        }
        fma_batch<RPB,HALF>(wq, c, hB, acc);          // consume batch k+1
        c += PF;
    }
    if (nfull & 1) {                      // last full batch sits in hA
        fma_batch<RPB,HALF>(wq, c, hA, acc);
        c += PF;
    }
    if (c < cto) {                        // guarded tail batch (<=1 latency)
        #pragma unroll
        for (int j = 0; j < PF; ++j)
            hA[j] = (c + j < cto) ? agload(&rbl[(abase + c + j)*64]) : 0.0f;
        #pragma unroll
        for (int j = 0; j < PF; ++j) {
            if (c + j < cto) {
                #pragma unroll
                for (int g = 0; g < HALF/4; ++g) {
                    const float4 w4 = *reinterpret_cast<const float4*>(&wq[(c + j)*RPB + 4*g]);
                    acc[4*g+0] += w4.x * hA[j];
                    acc[4*g+1] += w4.y * hA[j];
                    acc[4*g+2] += w4.z * hA[j];
                    acc[4*g+3] += w4.w * hA[j];
                }
            }
        }
    }
}

template<int RPB, int HALF>
__device__ __forceinline__ void mm_do(
    const float* __restrict__ rb, const float* __restrict__ wq,
    int c0, int a1, int b0, int c1, int r0s, int r1s, int r0l,
    float* __restrict__ red, int kq, int q0, int lane)
{
    float acc[HALF];
    #pragma unroll
    for (int q = 0; q < HALF; ++q) acc[q] = 0.0f;
    const float* __restrict__ rbl = rb + lane;
    mm_seg_pipe<RPB,HALF>(rbl, wq, c0, a1, r0s, acc);          // segment A
    mm_seg_pipe<RPB,HALF>(rbl, wq, b0, c1, r1s - r0l, acc);    // segment B
    #pragma unroll
    for (int q = 0; q < HALF; ++q)
        red[(kq*32 + q0 + q)*64 + lane] = acc[q];
}

__global__ void __launch_bounds__(NTHR7, 1) rnn_loop_v7(Params p)
{
    const int tid  = threadIdx.x;
    const int lane = tid & 63;          // batch
    const int wv   = tid >> 6;          // 0..7
    const int kq   = __builtin_amdgcn_readfirstlane(wv & 3);
    const int grp  = __builtin_amdgcn_readfirstlane(wv >> 2);
    const int bi   = blockIdx.x;

    int r = 0;
    while (bi >= c7_cs[r+1]) ++r;
    const int lc    = bi - c7_cs[r];
    const int rpb   = c7_rpb[r];
    const int row0  = lc * rpb;
    const int nr    = min(rpb, c_rows[r] - row0);
    const int u0    = c_dst[r] + row0;
    const int width = c_wid[r];
    const float tonic = c_ton[r];
    const int r0s = c_r0s[r], r0l = c_r0l[r], r1s = c_r1s[r];
    const float* __restrict__ wblk = p.Wc + c7_wb[r] + lc * width * rpb;

    __shared__ float red[4*32*64];     // [quarter][row<=32][batch]
    __shared__ float htile[32*65];     // padded transpose tile

    const int b = lane;

    // ---- init: x to regs, h(0) to hT0 ([unit][batch]) ----
    float xreg[4] = {0.f,0.f,0.f,0.f};
    #pragma unroll
    for (int pi = 0; pi < 4; ++pi) {
        int pr = wv + 8*pi;
        if (pr < nr) {
            int u = u0 + pr;
            xreg[pi] = p.xn[b*UNITS + u];
            agstore(&p.hT0[u*64 + b], p.hn[b*UNITS + u]);
        }
    }
    const bool outs_block = (bi >= 39 && bi < 103);
    const int  ob = bi - 39;
    gbarrier(p.cnt, NBLK7);

    const int c0 = __builtin_amdgcn_readfirstlane((width * kq) >> 2);
    const int c1 = __builtin_amdgcn_readfirstlane((width * (kq + 1)) >> 2);
    const int q0 = __builtin_amdgcn_readfirstlane(grp * (rpb >> 1));
    const int a1 = min(c1, r0l), b0 = max(c0, r0l);
    const float* __restrict__ wq = wblk + q0;

    for (int t = 0; t < NSTEP; ++t) {
        const float* __restrict__ rb = (t & 1) ? p.hT1 : p.hT0;
        float* __restrict__ wb = (t & 1) ? p.hT0 : p.hT1;

        // readout for previous step (h(t-1) in rb)
        if (outs_block && t > 0 && tid < 64) {
            float s = 0.0f;
            for (int jj = lane; jj < 359; jj += 64)
                s += agload(&rb[(2713+jj)*64 + ob]) * p.out_w[jj];
            #pragma unroll
            for (int off = 32; off > 0; off >>= 1)
                s += __shfl_down(s, off, 64);
            if (lane == 0) p.out[HSZ + (long long)ob*NSTEP + (t-1)] = s;
        }

        // prefetch per-step strided inputs (latency hides under matmul)
        float nh[4] = {0.f,0.f,0.f,0.f}, ih[4] = {0.f,0.f,0.f,0.f};
        #pragma unroll
        for (int pi = 0; pi < 4; ++pi) {
            int pr = wv + 8*pi;
            if (pr < nr) {
                int u = u0 + pr;
                nh[pi] = __builtin_nontemporal_load(&p.noise_hid[((long long)t*NBATCH + b)*UNITS + u]);
                ih[pi] = __builtin_nontemporal_load(&p.inhib[((long long)b*NSTEP + t)*UNITS + u]);
            }
        }
        const float inp_eff = p.inp[b*NSTEP + t] + NI_SCALE * p.noise_inp[t*NBATCH + b];
        const float cue_b   = p.cue[b*NSTEP + t];

        // ---- matmul: wave = (row-half grp, K-quarter kq), pipelined loads ----
        if (r == 0)
            mm_do<16,8 >(rb, wq, c0, a1, b0, c1, r0s, r1s, r0l, red, kq, q0, lane);
        else if (r == 1 || r == 6)
            mm_do<24,12>(rb, wq, c0, a1, b0, c1, r0s, r1s, r0l, red, kq, q0, lane);
        else
            mm_do<32,16>(rb, wq, c0, a1, b0, c1, r0s, r1s, r0l, red, kq, q0, lane);
        __syncthreads();

        // ---- reduce quarters (ascending) + pointwise ----
        #pragma unroll
        for (int pi = 0; pi < 4; ++pi) {
            int pr = wv + 8*pi;
            if (pr < nr) {
                int u = u0 + pr;
                float mm = red[(0*32 + pr)*64 + b];
                mm += red[(1*32 + pr)*64 + b];
                mm += red[(2*32 + pr)*64 + b];
                mm += red[(3*32 + pr)*64 + b];
                float drive = mm + tonic;
                if (u < 665) drive += inp_eff * p.inp_w[u];
                if (u >= 2201 && u < 2713) drive += cue_b;
                drive += ih[pi];
                drive += NH_SCALE * nh[pi];
                float xv = xreg[pi];
                xv = xv + 0.1f*(drive - xv);
                xreg[pi] = xv;
                float h = fmaxf(xv, 0.0f);
                agstore(&wb[u*64 + b], h);
                htile[pr*65 + b] = h;
            }
        }
        __syncthreads();
        {
            // hs output: [b][t][u]
            int rr = tid & 31, bb = tid >> 5;  // bb 0..15, four passes
            if (rr < nr) {
                #pragma unroll
                for (int rep = 0; rep < 4; ++rep) {
                    int bbb = bb + 16*rep;
                    long long o = (long long)bbb*(NSTEP*UNITS) + (long long)t*UNITS + (u0+rr);
                    __builtin_nontemporal_store(htile[rr*65 + bbb], &p.out[o]);
                }
            }
        }
        gbarrier(p.cnt, (unsigned)NBLK7*(t+2));
    }

    // final readout: h(499) in hT0 (500 even)
    if (outs_block && tid < 64) {
        const float* __restrict__ rb = p.hT0;
        float s = 0.0f;
        for (int jj = lane; jj < 359; jj += 64)
            s += agload(&rb[(2713+jj)*64 + ob]) * p.out_w[jj];
        #pragma unroll
        for (int off = 32; off > 0; off >>= 1)
            s += __shfl_down(s, off, 64);
        if (lane == 0) p.out[HSZ + (long long)ob*NSTEP + (NSTEP-1)] = s;
    }
}

// =============== round-0 fallback (verbatim logic, cg grid sync) ===============
__global__ void __launch_bounds__(256) rnn_loop_fb(Params p)
{
    cg::grid_group grid = cg::this_grid();
    const int tid  = threadIdx.x;
    const int lane = tid & 63;
    const int wv   = tid >> 6;
    const int bi   = blockIdx.x;

    int r = 0;
    while (bi >= c0_cs[r+1]) ++r;
    const int lc    = bi - c0_cs[r];
    const int row0  = lc * 8;
    const int nr    = min(8, c_rows[r] - row0);
    const int u0    = c_dst[r] + row0;
    const int width = c_wid[r];
    const float tonic = c_ton[r];
    const int r0s = c_r0s[r], r0l = c_r0l[r], r1s = c_r1s[r];
    const float* __restrict__ wr = p.Wc + c0_base[r] + row0 * width;

    __shared__ float red[4][8][64];
    __shared__ float htile[8*65];

    const int r2 = tid >> 6;
    const int b  = tid & 63;

    float xreg[2];
    #pragma unroll
    for (int pi = 0; pi < 2; ++pi) {
        int pr = r2 + 4*pi;
        xreg[pi] = 0.0f;
        if (pr < nr) {
            xreg[pi] = p.xn[b*UNITS + (u0+pr)];
            p.hT0[(u0+pr)*64 + b] = p.hn[b*UNITS + (u0+pr)];
        }
    }
    const bool outs_block = (bi >= 84 && bi < 148);
    grid.sync();

    const int c0 = (width * wv) >> 2;
    const int c1 = (width * (wv+1)) >> 2;
    const int a0 = c0, a1 = min(c1, r0l);
    const int b0 = max(c0, r0l), b1 = c1;

    for (int t = 0; t < NSTEP; ++t) {
        const float* __restrict__ rb = (t & 1) ? p.hT1 : p.hT0;
        float* __restrict__ wb = (t & 1) ? p.hT0 : p.hT1;

        if (outs_block && t > 0 && tid < 64) {
            int ob = bi - 84;
            float s = 0.0f;
            for (int jj = lane; jj < 359; jj += 64)
                s += rb[(2713+jj)*64 + ob] * p.out_w[jj];
            #pragma unroll
            for (int off = 32; off > 0; off >>= 1)
                s += __shfl_down(s, off, 64);
            if (lane == 0) p.out[HSZ + (long long)ob*NSTEP + (t-1)] = s;
        }

        float acc[8];
        #pragma unroll
        for (int q = 0; q < 8; ++q) acc[q] = 0.0f;

        #pragma unroll 4
        for (int c = a0; c < a1; ++c) {
            float hv = rb[(r0s + c)*64 + lane];
            #pragma unroll
            for (int q = 0; q < 8; ++q) acc[q] += wr[q*width + c] * hv;
        }
        #pragma unroll 4
        for (int c = b0; c < b1; ++c) {
            float hv = rb[(r1s + (c - r0l))*64 + lane];
            #pragma unroll
            for (int q = 0; q < 8; ++q) acc[q] += wr[q*width + c] * hv;
        }

        #pragma unroll
        for (int q = 0; q < 8; ++q) red[wv][q][lane] = acc[q];
        __syncthreads();

        const float inp_eff = p.inp[b*NSTEP + t] + NI_SCALE * p.noise_inp[t*NBATCH + b];
        const float cue_b   = p.cue[b*NSTEP + t];
        #pragma unroll
        for (int pi = 0; pi < 2; ++pi) {
            int pr = r2 + 4*pi;
            if (pr < nr) {
                int u = u0 + pr;
                float mm = red[0][pr][b] + red[1][pr][b] + red[2][pr][b] + red[3][pr][b];
                float drive = mm + tonic;
                if (u < 665) drive += inp_eff * p.inp_w[u];
                if (u >= 2201 && u < 2713) drive += cue_b;
                drive += p.inhib[((long long)b*NSTEP + t)*UNITS + u];
                drive += NH_SCALE * p.noise_hid[((long long)t*NBATCH + b)*UNITS + u];
                float xv = xreg[pi];
                xv = xv + 0.1f*(drive - xv);
                xreg[pi] = xv;
                float h = fmaxf(xv, 0.0f);
                wb[u*64 + b] = h;
                htile[pr*65 + b] = h;
            }
        }
        __syncthreads();
        {
            int rr = tid & 7, bb = tid >> 3;
            if (rr < nr) {
                long long o = (long long)bb*(NSTEP*UNITS) + (long long)t*UNITS + (u0+rr);
                p.out[o] = htile[rr*65 + bb];
                p.out[o + 32ll*NSTEP*UNITS] = htile[rr*65 + bb + 32];
            }
        }
        grid.sync();
    }

    if (outs_block && tid < 64) {
        int ob = bi - 84;
        const float* __restrict__ rb = p.hT0;
        float s = 0.0f;
        for (int jj = lane; jj < 359; jj += 64)
            s += rb[(2713+jj)*64 + ob] * p.out_w[jj];
        #pragma unroll
        for (int off = 32; off > 0; off >>= 1)
            s += __shfl_down(s, off, 64);
        if (lane == 0) p.out[HSZ + (long long)ob*NSTEP + (NSTEP-1)] = s;
    }
}

extern "C" void kernel_launch(void* const* d_in, const int* in_sizes, int n_in,
                              void* d_out, int out_size, void* d_ws, size_t ws_size,
                              hipStream_t stream)
{
    (void)in_sizes; (void)n_in; (void)out_size; (void)ws_size;
    const float* inp       = (const float*)d_in[0];
    const float* cue       = (const float*)d_in[1];
    const float* inhib     = (const float*)d_in[2];
    const float* hn        = (const float*)d_in[3];
    const float* xn        = (const float*)d_in[4];
    const float* noise_hid = (const float*)d_in[5];
    const float* noise_inp = (const float*)d_in[6];
    const float* str2str   = (const float*)d_in[7];
    const float* thal2alm  = (const float*)d_in[8];
    const float* thal2str  = (const float*)d_in[9];
    const float* alm2alm   = (const float*)d_in[10];
    const float* alm2str   = (const float*)d_in[11];
    const float* alm2thal  = (const float*)d_in[12];
    const float* str2snr   = (const float*)d_in[13];
    const float* str2gpe   = (const float*)d_in[14];
    const float* gpe2stn   = (const float*)d_in[15];
    const float* stn2snr   = (const float*)d_in[16];
    const float* snr2thal  = (const float*)d_in[17];
    const float* fsi2str   = (const float*)d_in[18];
    const float* thal2fsi  = (const float*)d_in[19];
    const float* alm2fsi   = (const float*)d_in[20];
    const float* fsi2fsi   = (const float*)d_in[21];
    const float* inp_w     = (const float*)d_in[22];
    const float* out_w     = (const float*)d_in[23];
    const int*   smask     = (const int*)d_in[24];

    float*    Wct = (float*)d_ws;
    float*    hT0 = Wct + WCT_FLOATS;           // [UNITS][64]
    float*    hT1 = hT0 + UNITS*64;
    unsigned* cnt = (unsigned*)(hT1 + UNITS*64);

    Params p;
    p.inp = inp; p.cue = cue; p.inhib = inhib; p.hn = hn; p.xn = xn;
    p.noise_hid = noise_hid; p.noise_inp = noise_inp;
    p.inp_w = inp_w; p.out_w = out_w; p.Wc = Wct;
    p.hT0 = hT0; p.hT1 = hT1; p.cnt = cnt; p.out = (float*)d_out;

    hipLaunchKernelGGL(build_w_v7, dim3((WCT_FLOATS+255)/256), dim3(256), 0, stream,
        str2str, thal2alm, thal2str, alm2alm, alm2str, alm2thal, str2snr, str2gpe,
        gpe2stn, stn2snr, snr2thal, fsi2str, thal2fsi, alm2fsi, fsi2fsi, smask, Wct, cnt);

    void* kargs[] = { &p };
    hipError_t ce = hipLaunchCooperativeKernel((void*)rnn_loop_v7,
                                               dim3(NBLK7), dim3(NTHR7), kargs, 0, stream);
    if (ce != hipSuccess) {
        (void)hipGetLastError();
        hipLaunchKernelGGL(build_w_r0, dim3((WC0_FLOATS+255)/256), dim3(256), 0, stream,
            str2str, thal2alm, thal2str, alm2alm, alm2str, alm2thal, str2snr, str2gpe,
            gpe2stn, stn2snr, snr2thal, fsi2str, thal2fsi, alm2fsi, fsi2fsi, smask, Wct);
        hipLaunchCooperativeKernel((void*)rnn_loop_fb,
                                   dim3(404), dim3(256), kargs, 0, stream);
    }
}